// Round 1
// baseline (26076.871 us; speedup 1.0000x reference)
//
#include <hip/hip_runtime.h>
#include <math.h>

// Problem constants
#define B 128
#define T 256
#define D 512
#define H 1024
#define KTOT 1536   // D + H
#define N4 4096     // 4*H

// Step-kernel tiling: 64 rows x 8 gate-cols (= 32 z-cols across the 4 gates)
#define RT 64
#define G 8
#define NTZ 32
#define KT 32

__global__ __launch_bounds__(256) void lstm_step(
    const float* __restrict__ x, const float* __restrict__ Wk,
    const float* __restrict__ bk, const float* __restrict__ h_prev,
    float* __restrict__ h_next, float* __restrict__ c_state, int t)
{
    __shared__ float As[KT][RT + 4];   // [k][r], pad to 68 floats
    __shared__ float Ws[KT][NTZ + 4];  // [k][cz], pad to 36 floats

    const int tid   = threadIdx.x;
    const int n0    = blockIdx.x * G;    // gate-column base within H
    const int rbase = blockIdx.y * RT;   // row base within B

    const int ty = tid >> 3;   // 0..31 -> rows 2*ty, 2*ty+1
    const int tx = tid & 7;    // 0..7  -> z-cols 4*tx .. 4*tx+3

    float acc[2][4];
    #pragma unroll
    for (int i = 0; i < 2; ++i)
        #pragma unroll
        for (int j = 0; j < 4; ++j) acc[i][j] = 0.f;

    for (int k0 = 0; k0 < KTOT; k0 += KT) {
        // ---- stage A tile: 64 rows x 32 k = 512 float4, 2 per thread ----
        #pragma unroll
        for (int it = 0; it < 2; ++it) {
            int f  = it * 256 + tid;
            int r  = f & 63;
            int kg = f >> 6;            // 0..7  (float4 group along k)
            int k  = k0 + kg * 4;
            int rg = rbase + r;
            float4 v;
            if (k < D) {
                // x[b][t][d] slice; k0 multiples of 32 so float4 never straddles D
                v = *(const float4*)&x[((size_t)rg * T + t) * D + k];
            } else {
                v = *(const float4*)&h_prev[(size_t)rg * H + (k - D)];
            }
            As[kg * 4 + 0][r] = v.x;
            As[kg * 4 + 1][r] = v.y;
            As[kg * 4 + 2][r] = v.z;
            As[kg * 4 + 3][r] = v.w;
        }
        // ---- stage W tile: 32 k x 32 z-cols = 256 float4, 1 per thread ----
        {
            int f   = tid;
            int cz4 = f & 7;          // which float4 group of z-cols
            int k   = f >> 3;         // 0..31
            int g   = cz4 >> 1;       // gate index 0..3 (i,j,f,o)
            int cc  = (cz4 & 1) * 4;  // offset within this block's 8 gate-cols
            float4 v = *(const float4*)&Wk[(size_t)(k0 + k) * N4 + g * H + n0 + cc];
            *(float4*)&Ws[k][cz4 * 4] = v;
        }
        __syncthreads();
        #pragma unroll
        for (int kk = 0; kk < KT; ++kk) {
            float2 a = *(const float2*)&As[kk][ty * 2];
            float4 w = *(const float4*)&Ws[kk][tx * 4];
            acc[0][0] += a.x * w.x; acc[0][1] += a.x * w.y;
            acc[0][2] += a.x * w.z; acc[0][3] += a.x * w.w;
            acc[1][0] += a.y * w.x; acc[1][1] += a.y * w.y;
            acc[1][2] += a.y * w.z; acc[1][3] += a.y * w.w;
        }
        __syncthreads();
    }

    // ---- regroup z through LDS so each thread sees its (i,j,f,o) tuple ----
    // reuse As as zs[cz][r] (32 x 68 >= 32 x 64)
    #pragma unroll
    for (int j = 0; j < 4; ++j) {
        As[tx * 4 + j][ty * 2 + 0] = acc[0][j];
        As[tx * 4 + j][ty * 2 + 1] = acc[1][j];
    }
    __syncthreads();

    // gates: 64 rows x 8 cols = 512 outputs, 2 per thread
    #pragma unroll
    for (int it = 0; it < 2; ++it) {
        int idx = it * 256 + tid;
        int r   = idx & 63;
        int nn  = idx >> 6;   // 0..7
        float zi = As[nn     ][r] + bk[0 * H + n0 + nn];
        float zj = As[8  + nn][r] + bk[1 * H + n0 + nn];
        float zf = As[16 + nn][r] + bk[2 * H + n0 + nn];
        float zo = As[24 + nn][r] + bk[3 * H + n0 + nn];
        size_t off = (size_t)(rbase + r) * H + n0 + nn;
        float cold = c_state[off];
        float si = 1.f / (1.f + __expf(-zi));
        float sf = 1.f / (1.f + __expf(-(zf + 1.0f)));  // forget bias 1.0
        float so = 1.f / (1.f + __expf(-zo));
        float tj = tanhf(zj);
        float cn = cold * sf + si * tj;
        float hn = so * tanhf(cn);
        c_state[off] = cn;
        h_next[off]  = hn;
    }
}

// out[128][1000] = h[128][1024] @ w[1024][1000] + b
__global__ __launch_bounds__(256) void proj_kernel(
    const float* __restrict__ h, const float* __restrict__ w,
    const float* __restrict__ bias, float* __restrict__ out)
{
    int cidx = blockIdx.x * 256 + threadIdx.x;  // 0..1023
    int bg   = blockIdx.y;                      // 0..7 -> 16 rows each
    bool valid = cidx < 1000;
    float acc[16];
    #pragma unroll
    for (int i = 0; i < 16; ++i) acc[i] = 0.f;

    for (int k = 0; k < H; k += 4) {
        float w0 = 0.f, w1 = 0.f, w2 = 0.f, w3 = 0.f;
        if (valid) {
            w0 = w[(size_t)(k + 0) * 1000 + cidx];
            w1 = w[(size_t)(k + 1) * 1000 + cidx];
            w2 = w[(size_t)(k + 2) * 1000 + cidx];
            w3 = w[(size_t)(k + 3) * 1000 + cidx];
        }
        #pragma unroll
        for (int i = 0; i < 16; ++i) {
            float4 hv = *(const float4*)&h[(size_t)(bg * 16 + i) * H + k];
            acc[i] += hv.x * w0 + hv.y * w1 + hv.z * w2 + hv.w * w3;
        }
    }
    if (valid) {
        #pragma unroll
        for (int i = 0; i < 16; ++i)
            out[(size_t)(bg * 16 + i) * 1000 + cidx] = acc[i] + bias[cidx];
    }
}

extern "C" void kernel_launch(void* const* d_in, const int* in_sizes, int n_in,
                              void* d_out, int out_size, void* d_ws, size_t ws_size,
                              hipStream_t stream) {
    const float* x  = (const float*)d_in[0];  // [B,T,D]
    const float* Wk = (const float*)d_in[1];  // [D+H, 4H]
    const float* bk = (const float*)d_in[2];  // [4H]
    const float* w  = (const float*)d_in[3];  // [H, C]
    const float* b  = (const float*)d_in[4];  // [C]
    float* out = (float*)d_out;               // [B, C]

    float* h0 = (float*)d_ws;                 // B*H floats
    float* h1 = h0 + (size_t)B * H;
    float* c  = h1 + (size_t)B * H;

    // ws is re-poisoned to 0xAA before every timed call — zero-init state.
    hipMemsetAsync(h0, 0, (size_t)B * H * sizeof(float), stream);
    hipMemsetAsync(c,  0, (size_t)B * H * sizeof(float), stream);

    dim3 grid(H / G, B / RT);   // 128 x 2 = 256 blocks
    for (int t = 0; t < T; ++t) {
        const float* hp = (t & 1) ? h1 : h0;
        float*       hn = (t & 1) ? h0 : h1;
        lstm_step<<<grid, dim3(256), 0, stream>>>(x, Wk, bk, hp, hn, c, t);
    }
    // t=255 (odd) wrote h0 -> final hidden state is h0
    proj_kernel<<<dim3(4, 8), dim3(256), 0, stream>>>(h0, w, b, out);
}

// Round 2
// 5603.717 us; speedup vs baseline: 4.6535x; 4.6535x over previous
//
#include <hip/hip_runtime.h>
#include <math.h>

// Problem constants
#define B 128
#define T 256
#define D 512
#define H 1024
#define KTOT 1536   // D + H
#define N4 4096     // 4*H

typedef short short8 __attribute__((ext_vector_type(8)));
typedef float f32x4 __attribute__((ext_vector_type(4)));

__device__ __forceinline__ unsigned short f2bf(float f) {
    unsigned int u = __builtin_bit_cast(unsigned int, f);
    unsigned int r = (u + 0x7fffu + ((u >> 16) & 1u)) >> 16;  // round-to-nearest-even
    return (unsigned short)r;
}
__device__ __forceinline__ float bf2f(unsigned short s) {
    unsigned int u = ((unsigned int)s) << 16;
    return __builtin_bit_cast(float, u);
}

// x fp32 [B][T][D] -> xb bf16 [T][B][D]  (contiguous per-step slices)
__global__ __launch_bounds__(256) void convert_x(
    const float* __restrict__ x, unsigned short* __restrict__ xb)
{
    int bid = blockIdx.x;          // t*B + b
    int t = bid >> 7;              // B = 128
    int b = bid & 127;
    int d = threadIdx.x * 2;
    const float2 v = *(const float2*)&x[((size_t)b * T + t) * D + d];
    unsigned int packed = (unsigned int)f2bf(v.x) | ((unsigned int)f2bf(v.y) << 16);
    *(unsigned int*)&xb[((size_t)t * B + b) * D + d] = packed;
}

// Wk fp32 [KTOT][N4] -> Wt bf16 [N4][KTOT]  (transposed, n-major)
__global__ __launch_bounds__(256) void convert_W(
    const float* __restrict__ Wk, unsigned short* __restrict__ Wt)
{
    __shared__ float tile[32][33];
    int nb = blockIdx.x;   // 0..127
    int kb = blockIdx.y;   // 0..47
    int tx = threadIdx.x & 31;
    int ty = threadIdx.x >> 5;   // 0..7
    #pragma unroll
    for (int i = 0; i < 4; ++i) {
        int k = kb * 32 + ty + i * 8;
        tile[ty + i * 8][tx] = Wk[(size_t)k * N4 + nb * 32 + tx];
    }
    __syncthreads();
    #pragma unroll
    for (int i = 0; i < 4; ++i) {
        int n = nb * 32 + ty + i * 8;
        Wt[(size_t)n * KTOT + kb * 32 + tx] = f2bf(tile[tx][ty + i * 8]);
    }
}

// One LSTM step. Block: 64 rows x 32 z-cols (8 gate-cols x 4 gates).
// 4 waves, m-split: wave w rows [rbase+16w, +16). Wave tile 16x32 via two
// mfma_f32_16x16x32_bf16. A-frags direct from global; W tile dbuf in LDS.
__global__ __launch_bounds__(256) void lstm_step(
    const unsigned short* __restrict__ xb,   // [T][B][D] bf16
    const unsigned short* __restrict__ Wt,   // [N4][KTOT] bf16
    const float* __restrict__ bk,            // [N4]
    const unsigned short* __restrict__ hprev,// [B][H] bf16
    unsigned short* __restrict__ hnext,      // [B][H] bf16
    float* __restrict__ cst,                 // [B][H] fp32
    int t)
{
    __shared__ unsigned short Ws[2][32][40];  // [buf][zcol][k] pad->80B rows
    __shared__ float zbuf[32][68];            // [zcol][row] pad

    const int tid   = threadIdx.x;
    const int n0    = blockIdx.x * 8;    // gate-col base within H
    const int rbase = blockIdx.y * 64;   // row base within B

    const int w    = tid >> 6;
    const int lane = tid & 63;
    const int mi   = lane & 15;
    const int q    = lane >> 4;

    const int row = rbase + w * 16 + mi;
    const unsigned short* xrow = xb + ((size_t)t * B + row) * D;
    const unsigned short* hrow = hprev + (size_t)row * H - 512;  // indexed by k>=512

    // staging: threads 0..127 -> zcol sc (0..31), k-group skg (0..3)
    const int sc  = tid >> 2;
    const int skg = tid & 3;
    const bool stager = tid < 128;
    const int zc = (sc >> 3) * H + n0 + (sc & 7);  // global z-column
    const unsigned short* wrow = Wt + (size_t)zc * KTOT + skg * 8;

    f32x4 acc0 = {0.f, 0.f, 0.f, 0.f};
    f32x4 acc1 = {0.f, 0.f, 0.f, 0.f};

    uint4 wreg;
    if (stager) {
        wreg = *(const uint4*)wrow;                 // k-tile 0
        *(uint4*)&Ws[0][sc][skg * 8] = wreg;
    }
    __syncthreads();

    #pragma unroll 4
    for (int it = 0; it < 48; ++it) {
        const int k0  = it * 32;
        const int cur = it & 1;
        if (stager && it + 1 < 48)
            wreg = *(const uint4*)(wrow + (it + 1) * 32);   // prefetch next tile

        const unsigned short* ap = (k0 < 512) ? (xrow + k0 + q * 8)
                                              : (hrow + k0 + q * 8);
        short8 a  = *(const short8*)ap;
        short8 b0 = *(const short8*)&Ws[cur][mi][q * 8];
        short8 b1 = *(const short8*)&Ws[cur][16 + mi][q * 8];
        acc0 = __builtin_amdgcn_mfma_f32_16x16x32_bf16(a, b0, acc0, 0, 0, 0);
        acc1 = __builtin_amdgcn_mfma_f32_16x16x32_bf16(a, b1, acc1, 0, 0, 0);

        if (stager && it + 1 < 48)
            *(uint4*)&Ws[cur ^ 1][sc][skg * 8] = wreg;
        __syncthreads();   // protects both buffers across iterations
    }

    // C/D layout: col = lane&15, row-in-tile = q*4 + reg
    #pragma unroll
    for (int g = 0; g < 4; ++g) {
        zbuf[mi][w * 16 + q * 4 + g]      = acc0[g];
        zbuf[16 + mi][w * 16 + q * 4 + g] = acc1[g];
    }
    __syncthreads();

    // gate pass: 64 rows x 8 gate-cols, 2 outputs/thread; nn fastest for coalescing
    #pragma unroll
    for (int itg = 0; itg < 2; ++itg) {
        int idx = itg * 256 + tid;
        int nn  = idx & 7;
        int r   = idx >> 3;   // 0..63
        float zi = zbuf[nn][r]      + bk[n0 + nn];
        float zj = zbuf[8 + nn][r]  + bk[H + n0 + nn];
        float zf = zbuf[16 + nn][r] + bk[2 * H + n0 + nn];
        float zo = zbuf[24 + nn][r] + bk[3 * H + n0 + nn];
        size_t off = (size_t)(rbase + r) * H + n0 + nn;
        float cold = cst[off];
        float si = 1.f / (1.f + __expf(-zi));
        float sf = 1.f / (1.f + __expf(-(zf + 1.0f)));  // forget bias 1.0
        float so = 1.f / (1.f + __expf(-zo));
        float tj = tanhf(zj);
        float cn = cold * sf + si * tj;
        float hn = so * tanhf(cn);
        cst[off]   = cn;
        hnext[off] = f2bf(hn);
    }
}

// out[128][1000] = h(bf16)[128][1024] @ w[1024][1000] + b
__global__ __launch_bounds__(256) void proj_kernel(
    const unsigned short* __restrict__ hb, const float* __restrict__ w,
    const float* __restrict__ bias, float* __restrict__ out)
{
    int cidx = blockIdx.x * 256 + threadIdx.x;  // 0..1023
    int bg   = blockIdx.y;                      // 0..7 -> 16 rows each
    bool valid = cidx < 1000;
    float acc[16];
    #pragma unroll
    for (int i = 0; i < 16; ++i) acc[i] = 0.f;

    for (int k = 0; k < H; k += 4) {
        float w0 = 0.f, w1 = 0.f, w2 = 0.f, w3 = 0.f;
        if (valid) {
            w0 = w[(size_t)(k + 0) * 1000 + cidx];
            w1 = w[(size_t)(k + 1) * 1000 + cidx];
            w2 = w[(size_t)(k + 2) * 1000 + cidx];
            w3 = w[(size_t)(k + 3) * 1000 + cidx];
        }
        #pragma unroll
        for (int i = 0; i < 16; ++i) {
            ushort4 hv = *(const ushort4*)&hb[(size_t)(bg * 16 + i) * H + k];
            acc[i] += bf2f(hv.x) * w0 + bf2f(hv.y) * w1
                    + bf2f(hv.z) * w2 + bf2f(hv.w) * w3;
        }
    }
    if (valid) {
        #pragma unroll
        for (int i = 0; i < 16; ++i)
            out[(size_t)(bg * 16 + i) * 1000 + cidx] = acc[i] + bias[cidx];
    }
}

extern "C" void kernel_launch(void* const* d_in, const int* in_sizes, int n_in,
                              void* d_out, int out_size, void* d_ws, size_t ws_size,
                              hipStream_t stream) {
    const float* x  = (const float*)d_in[0];  // [B,T,D]
    const float* Wk = (const float*)d_in[1];  // [D+H, 4H]
    const float* bk = (const float*)d_in[2];  // [4H]
    const float* w  = (const float*)d_in[3];  // [H, C]
    const float* b  = (const float*)d_in[4];  // [C]
    float* out = (float*)d_out;               // [B, C]

    // ws carve-up (bytes)
    char* p = (char*)d_ws;
    unsigned short* xb = (unsigned short*)p;                 p += (size_t)B * T * D * 2;  // 33.5 MB
    unsigned short* Wt = (unsigned short*)p;                 p += (size_t)N4 * KTOT * 2;  // 12.6 MB
    unsigned short* h0 = (unsigned short*)p;                 p += (size_t)B * H * 2;
    unsigned short* h1 = (unsigned short*)p;                 p += (size_t)B * H * 2;
    float*          c  = (float*)p;                          p += (size_t)B * H * 4;

    // ws is re-poisoned to 0xAA before every timed call — zero-init state.
    hipMemsetAsync(h0, 0, (size_t)B * H * 2, stream);
    hipMemsetAsync(c,  0, (size_t)B * H * 4, stream);

    convert_x<<<dim3(T * B), dim3(256), 0, stream>>>(x, xb);
    convert_W<<<dim3(N4 / 32, KTOT / 32), dim3(256), 0, stream>>>(Wk, Wt);

    dim3 grid(H / 8, B / 64);   // 128 x 2 = 256 blocks
    for (int t = 0; t < T; ++t) {
        const unsigned short* hp = (t & 1) ? h1 : h0;
        unsigned short*       hn = (t & 1) ? h0 : h1;
        lstm_step<<<grid, dim3(256), 0, stream>>>(xb, Wt, bk, hp, hn, c, t);
    }
    // t=255 (odd) wrote h0 -> final hidden state is h0
    proj_kernel<<<dim3(4, 8), dim3(256), 0, stream>>>(h0, w, b, out);
}